// Round 2
// baseline (476.953 us; speedup 1.0000x reference)
//
#include <hip/hip_runtime.h>
#include <hip/hip_bf16.h>

typedef _Float16 half8  __attribute__((ext_vector_type(8)));
typedef _Float16 half2v __attribute__((ext_vector_type(2)));
typedef float    f32x16 __attribute__((ext_vector_type(16)));

#define KC 32
#define DD 128
#define LL 4
#define NBLK 768      // 3 blocks/CU resident (~50.7KB LDS each -> ~152KB/CU)
#define WPB 4
#define NSLOT (NBLK*WPB)

// ---------------------------------------------------------------------------
// helpers
// ---------------------------------------------------------------------------
__device__ inline half2v pkrtz(float a, float b) {
  return __builtin_bit_cast(half2v, __builtin_amdgcn_cvt_pkrtz(a, b));
}
__device__ inline half2v shx2(half2v v, int d) {        // DS-pipe shuffle
  int i = __builtin_bit_cast(int, v);
  i = __shfl_xor(i, d);
  return __builtin_bit_cast(half2v, i);
}
__device__ inline half2v shl2(half2v v, int src) {      // DS-pipe bpermute
  int i = __builtin_bit_cast(int, v);
  i = __shfl(i, src);
  return __builtin_bit_cast(half2v, i);
}
// DPP cross-lane (VALU pipe, no DS): ctrl is a compile-time constant.
// 0xB1 = quad_perm xor1, 0x4E = quad_perm xor2,
// 0x141 = row_half_mirror (xor7), 0x140 = row_mirror (xor15).
template <int CTRL>
__device__ inline half2v dpp2(half2v v) {
  int i = __builtin_bit_cast(int, v);
  int r = __builtin_amdgcn_update_dpp(i, i, CTRL, 0xF, 0xF, true);
  return __builtin_bit_cast(half2v, r);
}
__device__ inline half2v pmax2(half2v a, half2v b) {
  half2v r;
  r[0] = a[0] > b[0] ? a[0] : b[0];
  r[1] = a[1] > b[1] ? a[1] : b[1];
  return r;
}
__device__ inline half2v sel8(const half2v* p, int i) {
  half2v a = (i & 1) ? p[1] : p[0];
  half2v b = (i & 1) ? p[3] : p[2];
  half2v c = (i & 1) ? p[5] : p[4];
  half2v d = (i & 1) ? p[7] : p[6];
  half2v e = (i & 2) ? b : a;
  half2v f = (i & 2) ? d : c;
  return (i & 4) ? f : e;
}

// ---------------------------------------------------------------------------
// Fused single kernel.
//   phases A-C: build Woodbury factors + f16 weight matrix in LDS (as before,
//   but with -0.5 folded into the q-columns and sqrt(0.5) into the z-columns
//   so the main loop needs only 5 accumulators instead of 6).
//   main: per-wave 32-row tiles, software-pipelined depth 1 -- next tile's
//   batch-0 loads are issued BEFORE the epilogue so ~8 KB/wave stays in
//   flight through the ~1300-cycle VALU epilogue (fixes the phase-locked
//   memory duty cycle that capped HBM at ~68% of achievable).
// ---------------------------------------------------------------------------
__global__ __launch_bounds__(256, 3) void mfa_fused(
    const float* __restrict__ x, const float* __restrict__ MU,
    const float* __restrict__ A, const float* __restrict__ D,
    const float* __restrict__ PI, float* __restrict__ out,
    int N, int ntiles, int iters)
{
  __shared__ int4 sWbuf[3072];           // 48 KB weights (fragment order)
  __shared__ float sMeta[672];           // Ri[32*16] | h[32*4] | cc[32]
  float* sMetaR = sMeta;
  float* sMetaH = sMeta + 512;
  float* sMetaC = sMeta + 640;

  const int tid = threadIdx.x;
  const int k   = tid >> 3;
  const int sub = tid & 7;
  const int dbase = k*DD + sub*16;

  // ---- phase A: partial sums over this thread's 16 d's ----
  float idv[16], muv[16];
  {
    float (*sPart)[8][16] = (float (*)[8][16])sWbuf;   // 16KB alias
    float p[16];
#pragma unroll
    for (int i = 0; i < 16; ++i) p[i] = 0.f;
#pragma unroll
    for (int di = 0; di < 16; ++di) {
      const float Dv = D[dbase + di];
      const float id = 1.0f/(Dv*Dv);
      const float mu = MU[dbase + di];
      idv[di] = id; muv[di] = mu;
      const float4 a4 = *(const float4*)(A + (size_t)(dbase + di)*LL);
      const float a[LL] = {a4.x, a4.y, a4.z, a4.w};
      int s = 0;
#pragma unroll
      for (int l = 0; l < LL; ++l) {
#pragma unroll
        for (int m2 = 0; m2 <= l; ++m2) { p[s] += a[l]*id*a[m2]; ++s; }
        p[10 + l] += mu*id*a[l];
      }
      p[14] += id*mu*mu;
      p[15] += __logf(Dv*Dv);
    }
#pragma unroll
    for (int i = 0; i < 16; ++i) sPart[k][sub][i] = p[i];
  }
  __syncthreads();

  // ---- phase B: one thread per component finalizes Woodbury ----
  if (tid < KC) {
    float (*sPart)[8][16] = (float (*)[8][16])sWbuf;
    const int kk = tid;
    float p[16];
#pragma unroll
    for (int i = 0; i < 16; ++i) p[i] = 0.f;
    for (int s = 0; s < 8; ++s)
#pragma unroll
      for (int i = 0; i < 16; ++i) p[i] += sPart[kk][s][i];

    float Lm[LL][LL];
    {
      int s = 0;
      for (int l = 0; l < LL; ++l)
        for (int m2 = 0; m2 <= l; ++m2) { Lm[l][m2] = p[s]; ++s; }
    }
    for (int l = 0; l < LL; ++l) Lm[l][l] += 1.0f;
    float cv[LL];
    for (int l = 0; l < LL; ++l) cv[l] = p[10 + l];
    const float t_const  = p[14];
    const float sumlogD2 = p[15];

    float Lo[LL][LL];
    for (int i = 0; i < LL; ++i)
      for (int j = 0; j < LL; ++j) Lo[i][j] = 0.f;
    for (int i = 0; i < LL; ++i) {
      float s = Lm[i][i];
      for (int m2 = 0; m2 < i; ++m2) s -= Lo[i][m2]*Lo[i][m2];
      Lo[i][i] = sqrtf(s);
      for (int j = i + 1; j < LL; ++j) {
        float t = Lm[j][i];
        for (int m2 = 0; m2 < i; ++m2) t -= Lo[j][m2]*Lo[i][m2];
        Lo[j][i] = t / Lo[i][i];
      }
    }
    float Ri[LL][LL];
    for (int i = 0; i < LL; ++i)
      for (int j = 0; j < LL; ++j) Ri[i][j] = 0.f;
    for (int i = 0; i < LL; ++i) {
      Ri[i][i] = 1.0f/Lo[i][i];
      for (int j = 0; j < i; ++j) {
        float s = 0.f;
        for (int m2 = j; m2 < i; ++m2) s += Lo[i][m2]*Ri[m2][j];
        Ri[i][j] = -s / Lo[i][i];
      }
    }
    for (int i = 0; i < LL; ++i)
      for (int j = 0; j < LL; ++j) sMetaR[kk*16 + i*4 + j] = Ri[i][j];
    for (int l = 0; l < LL; ++l) {
      float s = 0.f;
      for (int m2 = 0; m2 <= l; ++m2) s += Ri[l][m2]*cv[m2];
      sMetaH[kk*LL + l] = s;
    }
    float logdetL = 0.f;
    for (int i = 0; i < LL; ++i) logdetL += __logf(Lo[i][i]);
    logdetL *= 2.0f;
    const float dlog2pi = 235.24826473f;  // 128*log(2*pi)
    sMetaC[kk] = PI[kk] - 0.5f*(dlog2pi + logdetL + sumlogD2) - 0.5f*t_const;
  }
  __syncthreads();

  // ---- phase C: weights in 32x32x16 MFMA B-fragment order ----
  // element = W[col = 32t + (lane&31)][dd = 16s + 8*(lane>>5) + j]
  // tile 0 (q): -0.5*iD  (pairs with x^2 frags; -0.5 folded -> single U acc)
  // tile 1 (r): iD*MU
  // tiles 2-5 (z): sqrt(0.5) * iD * (A @ Ri^T)   (0.5 of term2 folded)
  {
    float Rm[LL][LL];
#pragma unroll
    for (int l = 0; l < LL; ++l)
#pragma unroll
      for (int m = 0; m < LL; ++m) Rm[l][m] = sMetaR[k*16 + l*4 + m];
    half8* sW8w = (half8*)sWbuf;
    const float sc = 0.70710678118654752f;
#pragma unroll
    for (int h2 = 0; h2 < 2; ++h2) {
      half8 vq, vr, vz0, vz1, vz2, vz3;
#pragma unroll
      for (int j = 0; j < 8; ++j) {
        const int di = 8*h2 + j;
        const float id = idv[di];
        const float mu = muv[di];
        const float4 a4 = *(const float4*)(A + (size_t)(dbase + di)*LL);
        vq[j] = (_Float16)(-0.5f*id);
        vr[j] = (_Float16)(id*mu);
        const float s0 = a4.x*Rm[0][0];
        const float s1 = a4.x*Rm[1][0] + a4.y*Rm[1][1];
        const float s2 = a4.x*Rm[2][0] + a4.y*Rm[2][1] + a4.z*Rm[2][2];
        const float s3 = a4.x*Rm[3][0] + a4.y*Rm[3][1] + a4.z*Rm[3][2]
                       + a4.w*Rm[3][3];
        vz0[j] = (_Float16)(sc*id*s0);
        vz1[j] = (_Float16)(sc*id*s1);
        vz2[j] = (_Float16)(sc*id*s2);
        vz3[j] = (_Float16)(sc*id*s3);
      }
      const int lq = (h2 << 5) | k;
      sW8w[(0*8 + sub)*64 + lq] = vq;
      sW8w[(1*8 + sub)*64 + lq] = vr;
      const int tz = 2 + (k >> 3);
      const int lz = (h2 << 5) | ((k & 7) << 2);
      sW8w[(tz*8 + sub)*64 + lz + 0] = vz0;
      sW8w[(tz*8 + sub)*64 + lz + 1] = vz1;
      sW8w[(tz*8 + sub)*64 + lz + 2] = vz2;
      sW8w[(tz*8 + sub)*64 + lz + 3] = vz3;
    }
  }
  __syncthreads();   // weights + meta visible

  // ---- main loop: 4 waves/block, one 32-row tile per wave per round ----
  const half8* sW8 = (const half8*)sWbuf;
  const int wv = tid >> 6, lane = tid & 63;
  const int c = lane & 31;                        // component/col index
  const int h = lane >> 5;                        // row-half
  const float cc = sMetaC[c];
  float hz[4];                                    // sqrt(0.5)-scaled h
#pragma unroll
  for (int zt = 0; zt < 4; ++zt)
    hz[zt] = 0.70710678118654752f * sMetaH[(8*zt + (c >> 2))*4 + (c & 3)];
  // transport source lane: t2 for k=c lives (replicated per quad) where
  // (src&31)>>2 == c&7; keep within own 32-lane half.
  const int srcl = (lane & 32) | ((c & 7) << 2) | (c & 3);

  // row pointer for the tile of iteration `it` (clamped: also covers
  // tile >= ntiles, whose rows land past N)
  const int tbase = (int)blockIdx.x*WPB + wv;
  auto rowptr = [&](int it) -> const float* {
    int row = (it*NSLOT + tbase)*32 + c;
    if (row >= N) row = N - 1;
    return x + (size_t)row*DD + h*8;
  };

  // prologue: issue batch0 (ss=0..3) of tile 0
  const float* xr = rowptr(0);
  float4 xvP[8];
#pragma unroll
  for (int s = 0; s < 4; ++s) {
    xvP[2*s]     = *(const float4*)(xr + s*16);
    xvP[2*s + 1] = *(const float4*)(xr + s*16 + 4);
  }

  for (int it = 0; it < iters; ++it) {
    const int tile = it*NSLOT + tbase;

    // issue batch1 (ss=4..7) of current tile
    float4 xvB[8];
#pragma unroll
    for (int s = 0; s < 4; ++s) {
      xvB[2*s]     = *(const float4*)(xr + (4 + s)*16);
      xvB[2*s + 1] = *(const float4*)(xr + (4 + s)*16 + 4);
    }

    f32x16 acc[5];
#pragma unroll
    for (int t = 0; t < 5; ++t)
#pragma unroll
      for (int r = 0; r < 16; ++r) acc[t][r] = 0.f;

    // MFMA ss=0..3 from xvP (xvB in flight)
#pragma unroll
    for (int ss = 0; ss < 4; ++ss) {
      const float4 a = xvP[2*ss], b = xvP[2*ss + 1];
      union { half8 v; half2v p[4]; } hx, hx2;
      hx.p[0] = pkrtz(a.x, a.y);
      hx.p[1] = pkrtz(a.z, a.w);
      hx.p[2] = pkrtz(b.x, b.y);
      hx.p[3] = pkrtz(b.z, b.w);
      hx2.v = hx.v * hx.v;                       // packed f16 squares
      // U tile: q-part (x^2 vs -0.5*iD); spaced from r-part by the z MFMAs
      acc[0] = __builtin_amdgcn_mfma_f32_32x32x16_f16(
          hx2.v, sW8[(0*8 + ss)*64 + lane], acc[0], 0, 0, 0);
#pragma unroll
      for (int t = 0; t < 4; ++t)
        acc[1 + t] = __builtin_amdgcn_mfma_f32_32x32x16_f16(
            hx.v, sW8[((2 + t)*8 + ss)*64 + lane], acc[1 + t], 0, 0, 0);
      acc[0] = __builtin_amdgcn_mfma_f32_32x32x16_f16(
          hx.v, sW8[(1*8 + ss)*64 + lane], acc[0], 0, 0, 0);
    }

    // prefetch batch0 of NEXT tile (xvP regs are dead now) -- keeps 8 loads
    // outstanding through the epilogue
    const float* xrN = rowptr(it + 1);
#pragma unroll
    for (int s = 0; s < 4; ++s) {
      xvP[2*s]     = *(const float4*)(xrN + s*16);
      xvP[2*s + 1] = *(const float4*)(xrN + s*16 + 4);
    }
    xr = xrN;

    // MFMA ss=4..7 from xvB
#pragma unroll
    for (int ss = 4; ss < 8; ++ss) {
      const float4 a = xvB[2*(ss - 4)], b = xvB[2*(ss - 4) + 1];
      union { half8 v; half2v p[4]; } hx, hx2;
      hx.p[0] = pkrtz(a.x, a.y);
      hx.p[1] = pkrtz(a.z, a.w);
      hx.p[2] = pkrtz(b.x, b.y);
      hx.p[3] = pkrtz(b.z, b.w);
      hx2.v = hx.v * hx.v;
      acc[0] = __builtin_amdgcn_mfma_f32_32x32x16_f16(
          hx2.v, sW8[(0*8 + ss)*64 + lane], acc[0], 0, 0, 0);
#pragma unroll
      for (int t = 0; t < 4; ++t)
        acc[1 + t] = __builtin_amdgcn_mfma_f32_32x32x16_f16(
            hx.v, sW8[((2 + t)*8 + ss)*64 + lane], acc[1 + t], 0, 0, 0);
      acc[0] = __builtin_amdgcn_mfma_f32_32x32x16_f16(
          hx.v, sW8[(1*8 + ss)*64 + lane], acc[0], 0, 0, 0);
    }

    if (tile >= ntiles) continue;   // (wave-uniform) dummy tail tile

    // ---- epilogue (C layout: col = c = component k; 16 regs = 16 rows) ----
    // u(row r, k=c) with folded constant: acc[0] = -0.5*t_quad + t_cross
    float vp[16];
#pragma unroll
    for (int r = 0; r < 16; ++r)
      vp[r] = acc[0][r] + cc;

    // t2: e'^2 packed (e' = sqrt(0.5)*e), quad-reduce over l via DPP
    half2v tq[4][8];
#pragma unroll
    for (int zt = 0; zt < 4; ++zt)
#pragma unroll
      for (int i = 0; i < 8; ++i) {
        const float e0 = acc[1 + zt][2*i]     - hz[zt];
        const float e1 = acc[1 + zt][2*i + 1] - hz[zt];
        half2v p = pkrtz(e0*e0, e1*e1);
        p = p + dpp2<0xB1>(p);     // xor 1
        p = p + dpp2<0x4E>(p);     // xor 2
        tq[zt][i] = p;
      }
    // transport t2 to its k-owner lane (k = c): pull all 4 tile arrays from
    // srcl, select by zt* = c>>3
#pragma unroll
    for (int i = 0; i < 8; ++i) {
      half2v b0 = shl2(tq[0][i], srcl);
      half2v b1 = shl2(tq[1][i], srcl);
      half2v b2 = shl2(tq[2][i], srcl);
      half2v b3 = shl2(tq[3][i], srcl);
      half2v m01 = (c & 8)  ? b1 : b0;
      half2v m23 = (c & 8)  ? b3 : b2;
      half2v st  = (c & 16) ? m23 : m01;
      vp[2*i]     += (float)st[0];
      vp[2*i + 1] += (float)st[1];
    }

    // per-row max over the 32 k-lanes (packed fp16; DPP for xor1/2/4/8).
    half2v pm[8];
#pragma unroll
    for (int i = 0; i < 8; ++i)
      pm[i] = pkrtz(vp[2*i], vp[2*i + 1]);
#pragma unroll
    for (int i = 0; i < 8; ++i) {
      pm[i] = pmax2(pm[i], dpp2<0xB1>(pm[i]));
      pm[i] = pmax2(pm[i], dpp2<0x4E>(pm[i]));
      pm[i] = pmax2(pm[i], dpp2<0x141>(pm[i]));
      pm[i] = pmax2(pm[i], dpp2<0x140>(pm[i]));
      pm[i] = pmax2(pm[i], shx2(pm[i], 16));
    }

    // exp + packed sum reduction (same ladder)
    half2v ps[8];
#pragma unroll
    for (int i = 0; i < 8; ++i) {
      const float e0 = __expf(vp[2*i]     - (float)pm[i][0]);
      const float e1 = __expf(vp[2*i + 1] - (float)pm[i][1]);
      ps[i] = pkrtz(e0, e1);
    }
#pragma unroll
    for (int i = 0; i < 8; ++i) {
      ps[i] = ps[i] + dpp2<0xB1>(ps[i]);
      ps[i] = ps[i] + dpp2<0x4E>(ps[i]);
      ps[i] = ps[i] + dpp2<0x141>(ps[i]);
      ps[i] = ps[i] + dpp2<0x140>(ps[i]);
      ps[i] = ps[i] + shx2(ps[i], 16);
    }

    // write: lanes c<16 of each half cover the 32 rows
    if (c < 16) {
      const half2v S = sel8(ps, c >> 1);
      const half2v M = sel8(pm, c >> 1);
      const float sum = (c & 1) ? (float)S[1] : (float)S[0];
      const float mx  = (c & 1) ? (float)M[1] : (float)M[0];
      const int rw = tile*32 + (c & 3) + 8*(c >> 2) + 4*h;
      if (rw < N) out[rw] = mx + __logf(sum);
    }
  }
}

extern "C" void kernel_launch(void* const* d_in, const int* in_sizes, int n_in,
                              void* d_out, int out_size, void* d_ws, size_t ws_size,
                              hipStream_t stream) {
  (void)n_in; (void)out_size; (void)d_ws; (void)ws_size;
  const float* x  = (const float*)d_in[0];
  const float* MU = (const float*)d_in[1];
  const float* A  = (const float*)d_in[2];
  const float* D  = (const float*)d_in[3];
  const float* PI = (const float*)d_in[4];
  float* out = (float*)d_out;

  const int N = in_sizes[0] / DD;
  const int ntiles = (N + 31) / 32;
  const int iters  = (ntiles + NSLOT - 1) / NSLOT;
  hipLaunchKernelGGL(mfa_fused, dim3(NBLK), dim3(256), 0, stream,
                     x, MU, A, D, PI, out, N, ntiles, iters);
}

// Round 3
// 369.964 us; speedup vs baseline: 1.2892x; 1.2892x over previous
//
#include <hip/hip_runtime.h>
#include <hip/hip_bf16.h>

typedef _Float16 half8  __attribute__((ext_vector_type(8)));
typedef _Float16 half2v __attribute__((ext_vector_type(2)));
typedef float    f32x16 __attribute__((ext_vector_type(16)));

#define KC 32
#define DD 128
#define LL 4
#define NBLK 512      // 2 blocks/CU resident (VGPR-limited: 256 regs/wave)
#define WPB 4
#define NSLOT (NBLK*WPB)

// ---------------------------------------------------------------------------
// helpers
// ---------------------------------------------------------------------------
__device__ inline half2v pkrtz(float a, float b) {
  return __builtin_bit_cast(half2v, __builtin_amdgcn_cvt_pkrtz(a, b));
}
__device__ inline half2v shx2(half2v v, int d) {        // DS-pipe shuffle
  int i = __builtin_bit_cast(int, v);
  i = __shfl_xor(i, d);
  return __builtin_bit_cast(half2v, i);
}
__device__ inline half2v shl2(half2v v, int src) {      // DS-pipe bpermute
  int i = __builtin_bit_cast(int, v);
  i = __shfl(i, src);
  return __builtin_bit_cast(half2v, i);
}
// DPP cross-lane (VALU pipe, no DS): ctrl is a compile-time constant.
// 0xB1 = quad_perm xor1, 0x4E = quad_perm xor2,
// 0x141 = row_half_mirror (xor7), 0x140 = row_mirror (xor15).
template <int CTRL>
__device__ inline half2v dpp2(half2v v) {
  int i = __builtin_bit_cast(int, v);
  int r = __builtin_amdgcn_update_dpp(i, i, CTRL, 0xF, 0xF, true);
  return __builtin_bit_cast(half2v, r);
}
__device__ inline half2v pmax2(half2v a, half2v b) {
  half2v r;
  r[0] = a[0] > b[0] ? a[0] : b[0];
  r[1] = a[1] > b[1] ? a[1] : b[1];
  return r;
}
__device__ inline half2v sel8(const half2v* p, int i) {
  half2v a = (i & 1) ? p[1] : p[0];
  half2v b = (i & 1) ? p[3] : p[2];
  half2v c = (i & 1) ? p[5] : p[4];
  half2v d = (i & 1) ? p[7] : p[6];
  half2v e = (i & 2) ? b : a;
  half2v f = (i & 2) ? d : c;
  return (i & 4) ? f : e;
}

// ---------------------------------------------------------------------------
// Fused single kernel.
//   phases A-C: build Woodbury factors + f16 weight matrix in LDS (-0.5
//   folded into q-columns, sqrt(0.5) into z-columns -> 5 accumulators).
//   main: per-wave 32-row tiles, FULL-tile double-buffered register prefetch:
//   the next tile's 16 KB is issued at the top of each step and stays in
//   flight through the current tile's MFMAs + epilogue. 8 waves/CU x 16 KB
//   = 128 KB/CU outstanding >> BW-latency product -> HBM stays saturated.
//   Occupancy deliberately 2 waves/SIMD (256-VGPR budget) so the two 64-reg
//   x buffers + 80-reg accumulator fit WITHOUT spilling (R2's failure mode).
// ---------------------------------------------------------------------------
__global__ __launch_bounds__(256, 2) void mfa_fused(
    const float* __restrict__ x, const float* __restrict__ MU,
    const float* __restrict__ A, const float* __restrict__ D,
    const float* __restrict__ PI, float* __restrict__ out,
    int N, int ntiles, int iters)
{
  __shared__ int4 sWbuf[3072];           // 48 KB weights (fragment order)
  __shared__ float sMeta[672];           // Ri[32*16] | h[32*4] | cc[32]
  float* sMetaR = sMeta;
  float* sMetaH = sMeta + 512;
  float* sMetaC = sMeta + 640;

  const int tid = threadIdx.x;
  const int k   = tid >> 3;
  const int sub = tid & 7;
  const int dbase = k*DD + sub*16;

  // ---- phase A: partial sums over this thread's 16 d's ----
  float idv[16], muv[16];
  {
    float (*sPart)[8][16] = (float (*)[8][16])sWbuf;   // 16KB alias
    float p[16];
#pragma unroll
    for (int i = 0; i < 16; ++i) p[i] = 0.f;
#pragma unroll
    for (int di = 0; di < 16; ++di) {
      const float Dv = D[dbase + di];
      const float id = 1.0f/(Dv*Dv);
      const float mu = MU[dbase + di];
      idv[di] = id; muv[di] = mu;
      const float4 a4 = *(const float4*)(A + (size_t)(dbase + di)*LL);
      const float a[LL] = {a4.x, a4.y, a4.z, a4.w};
      int s = 0;
#pragma unroll
      for (int l = 0; l < LL; ++l) {
#pragma unroll
        for (int m2 = 0; m2 <= l; ++m2) { p[s] += a[l]*id*a[m2]; ++s; }
        p[10 + l] += mu*id*a[l];
      }
      p[14] += id*mu*mu;
      p[15] += __logf(Dv*Dv);
    }
#pragma unroll
    for (int i = 0; i < 16; ++i) sPart[k][sub][i] = p[i];
  }
  __syncthreads();

  // ---- phase B: one thread per component finalizes Woodbury ----
  if (tid < KC) {
    float (*sPart)[8][16] = (float (*)[8][16])sWbuf;
    const int kk = tid;
    float p[16];
#pragma unroll
    for (int i = 0; i < 16; ++i) p[i] = 0.f;
    for (int s = 0; s < 8; ++s)
#pragma unroll
      for (int i = 0; i < 16; ++i) p[i] += sPart[kk][s][i];

    float Lm[LL][LL];
    {
      int s = 0;
      for (int l = 0; l < LL; ++l)
        for (int m2 = 0; m2 <= l; ++m2) { Lm[l][m2] = p[s]; ++s; }
    }
    for (int l = 0; l < LL; ++l) Lm[l][l] += 1.0f;
    float cv[LL];
    for (int l = 0; l < LL; ++l) cv[l] = p[10 + l];
    const float t_const  = p[14];
    const float sumlogD2 = p[15];

    float Lo[LL][LL];
    for (int i = 0; i < LL; ++i)
      for (int j = 0; j < LL; ++j) Lo[i][j] = 0.f;
    for (int i = 0; i < LL; ++i) {
      float s = Lm[i][i];
      for (int m2 = 0; m2 < i; ++m2) s -= Lo[i][m2]*Lo[i][m2];
      Lo[i][i] = sqrtf(s);
      for (int j = i + 1; j < LL; ++j) {
        float t = Lm[j][i];
        for (int m2 = 0; m2 < i; ++m2) t -= Lo[j][m2]*Lo[i][m2];
        Lo[j][i] = t / Lo[i][i];
      }
    }
    float Ri[LL][LL];
    for (int i = 0; i < LL; ++i)
      for (int j = 0; j < LL; ++j) Ri[i][j] = 0.f;
    for (int i = 0; i < LL; ++i) {
      Ri[i][i] = 1.0f/Lo[i][i];
      for (int j = 0; j < i; ++j) {
        float s = 0.f;
        for (int m2 = j; m2 < i; ++m2) s += Lo[i][m2]*Ri[m2][j];
        Ri[i][j] = -s / Lo[i][i];
      }
    }
    for (int i = 0; i < LL; ++i)
      for (int j = 0; j < LL; ++j) sMetaR[kk*16 + i*4 + j] = Ri[i][j];
    for (int l = 0; l < LL; ++l) {
      float s = 0.f;
      for (int m2 = 0; m2 <= l; ++m2) s += Ri[l][m2]*cv[m2];
      sMetaH[kk*LL + l] = s;
    }
    float logdetL = 0.f;
    for (int i = 0; i < LL; ++i) logdetL += __logf(Lo[i][i]);
    logdetL *= 2.0f;
    const float dlog2pi = 235.24826473f;  // 128*log(2*pi)
    sMetaC[kk] = PI[kk] - 0.5f*(dlog2pi + logdetL + sumlogD2) - 0.5f*t_const;
  }
  __syncthreads();

  // ---- phase C: weights in 32x32x16 MFMA B-fragment order ----
  // element = W[col = 32t + (lane&31)][dd = 16s + 8*(lane>>5) + j]
  // tile 0 (q): -0.5*iD ; tile 1 (r): iD*MU ; tiles 2-5 (z): sqrt(.5)*G
  {
    float Rm[LL][LL];
#pragma unroll
    for (int l = 0; l < LL; ++l)
#pragma unroll
      for (int m = 0; m < LL; ++m) Rm[l][m] = sMetaR[k*16 + l*4 + m];
    half8* sW8w = (half8*)sWbuf;
    const float sc = 0.70710678118654752f;
#pragma unroll
    for (int h2 = 0; h2 < 2; ++h2) {
      half8 vq, vr, vz0, vz1, vz2, vz3;
#pragma unroll
      for (int j = 0; j < 8; ++j) {
        const int di = 8*h2 + j;
        const float id = idv[di];
        const float mu = muv[di];
        const float4 a4 = *(const float4*)(A + (size_t)(dbase + di)*LL);
        vq[j] = (_Float16)(-0.5f*id);
        vr[j] = (_Float16)(id*mu);
        const float s0 = a4.x*Rm[0][0];
        const float s1 = a4.x*Rm[1][0] + a4.y*Rm[1][1];
        const float s2 = a4.x*Rm[2][0] + a4.y*Rm[2][1] + a4.z*Rm[2][2];
        const float s3 = a4.x*Rm[3][0] + a4.y*Rm[3][1] + a4.z*Rm[3][2]
                       + a4.w*Rm[3][3];
        vz0[j] = (_Float16)(sc*id*s0);
        vz1[j] = (_Float16)(sc*id*s1);
        vz2[j] = (_Float16)(sc*id*s2);
        vz3[j] = (_Float16)(sc*id*s3);
      }
      const int lq = (h2 << 5) | k;
      sW8w[(0*8 + sub)*64 + lq] = vq;
      sW8w[(1*8 + sub)*64 + lq] = vr;
      const int tz = 2 + (k >> 3);
      const int lz = (h2 << 5) | ((k & 7) << 2);
      sW8w[(tz*8 + sub)*64 + lz + 0] = vz0;
      sW8w[(tz*8 + sub)*64 + lz + 1] = vz1;
      sW8w[(tz*8 + sub)*64 + lz + 2] = vz2;
      sW8w[(tz*8 + sub)*64 + lz + 3] = vz3;
    }
  }
  __syncthreads();   // weights + meta visible

  // ---- main loop: full-tile double-buffered register prefetch ----
  const half8* sW8 = (const half8*)sWbuf;
  const int wv = tid >> 6, lane = tid & 63;
  const int c = lane & 31;                        // component/col index
  const int h = lane >> 5;                        // row-half
  const float cc = sMetaC[c];
  float hz[4];                                    // sqrt(0.5)-scaled h
#pragma unroll
  for (int zt = 0; zt < 4; ++zt)
    hz[zt] = 0.70710678118654752f * sMetaH[(8*zt + (c >> 2))*4 + (c & 3)];
  const int srcl = (lane & 32) | ((c & 7) << 2) | (c & 3);
  const int tbase = (int)blockIdx.x*WPB + wv;

  float4 xA[16], xB[16];

  // prologue: load ALL of tile 0 into xA
  {
    int row0 = tbase*32 + c;
    if (row0 >= N) row0 = N - 1;
    const float* xr = x + (size_t)row0*DD + h*8;
#pragma unroll
    for (int s = 0; s < 8; ++s) {
      xA[2*s]     = *(const float4*)(xr + s*16);
      xA[2*s + 1] = *(const float4*)(xr + s*16 + 4);
    }
  }

  // One pipeline step: prefetch tile (IT+1) into XN, compute tile IT from XC.
#define STEP(XC, XN, IT)                                                      \
  {                                                                           \
    const int tile = (IT)*NSLOT + tbase;                                      \
    /* issue next tile's 16 loads first: in flight through MFMA + epilogue */ \
    {                                                                         \
      int rowN = ((IT) + 1)*NSLOT*32 + tbase*32 + c;                          \
      if (rowN >= N) rowN = N - 1;                                            \
      const float* xrN = x + (size_t)rowN*DD + h*8;                           \
      _Pragma("unroll")                                                       \
      for (int s = 0; s < 8; ++s) {                                           \
        XN[2*s]     = *(const float4*)(xrN + s*16);                           \
        XN[2*s + 1] = *(const float4*)(xrN + s*16 + 4);                       \
      }                                                                       \
    }                                                                         \
    f32x16 acc[5];                                                            \
    _Pragma("unroll")                                                         \
    for (int t = 0; t < 5; ++t)                                               \
      _Pragma("unroll")                                                       \
      for (int r = 0; r < 16; ++r) acc[t][r] = 0.f;                           \
    _Pragma("unroll")                                                         \
    for (int ss = 0; ss < 8; ++ss) {                                          \
      const float4 a = XC[2*ss], b = XC[2*ss + 1];                            \
      union { half8 v; half2v p[4]; } hx, hx2;                                \
      hx.p[0] = pkrtz(a.x, a.y);                                              \
      hx.p[1] = pkrtz(a.z, a.w);                                              \
      hx.p[2] = pkrtz(b.x, b.y);                                              \
      hx.p[3] = pkrtz(b.z, b.w);                                              \
      hx2.v = hx.v * hx.v;                                                    \
      acc[0] = __builtin_amdgcn_mfma_f32_32x32x16_f16(                        \
          hx2.v, sW8[(0*8 + ss)*64 + lane], acc[0], 0, 0, 0);                 \
      _Pragma("unroll")                                                       \
      for (int t = 0; t < 4; ++t)                                             \
        acc[1 + t] = __builtin_amdgcn_mfma_f32_32x32x16_f16(                  \
            hx.v, sW8[((2 + t)*8 + ss)*64 + lane], acc[1 + t], 0, 0, 0);      \
      acc[0] = __builtin_amdgcn_mfma_f32_32x32x16_f16(                        \
          hx.v, sW8[(1*8 + ss)*64 + lane], acc[0], 0, 0, 0);                  \
    }                                                                         \
    if (tile < ntiles) {                                                      \
      float vp[16];                                                           \
      _Pragma("unroll")                                                       \
      for (int r = 0; r < 16; ++r) vp[r] = acc[0][r] + cc;                    \
      half2v tq[4][8];                                                        \
      _Pragma("unroll")                                                       \
      for (int zt = 0; zt < 4; ++zt)                                          \
        _Pragma("unroll")                                                     \
        for (int i = 0; i < 8; ++i) {                                         \
          const float e0 = acc[1 + zt][2*i]     - hz[zt];                     \
          const float e1 = acc[1 + zt][2*i + 1] - hz[zt];                     \
          half2v p = pkrtz(e0*e0, e1*e1);                                     \
          p = p + dpp2<0xB1>(p);                                              \
          p = p + dpp2<0x4E>(p);                                              \
          tq[zt][i] = p;                                                      \
        }                                                                     \
      _Pragma("unroll")                                                       \
      for (int i = 0; i < 8; ++i) {                                           \
        half2v b0 = shl2(tq[0][i], srcl);                                     \
        half2v b1 = shl2(tq[1][i], srcl);                                     \
        half2v b2 = shl2(tq[2][i], srcl);                                     \
        half2v b3 = shl2(tq[3][i], srcl);                                     \
        half2v m01 = (c & 8)  ? b1 : b0;                                      \
        half2v m23 = (c & 8)  ? b3 : b2;                                      \
        half2v st  = (c & 16) ? m23 : m01;                                    \
        vp[2*i]     += (float)st[0];                                          \
        vp[2*i + 1] += (float)st[1];                                          \
      }                                                                       \
      half2v pm[8];                                                           \
      _Pragma("unroll")                                                       \
      for (int i = 0; i < 8; ++i) pm[i] = pkrtz(vp[2*i], vp[2*i + 1]);        \
      _Pragma("unroll")                                                       \
      for (int i = 0; i < 8; ++i) {                                           \
        pm[i] = pmax2(pm[i], dpp2<0xB1>(pm[i]));                              \
        pm[i] = pmax2(pm[i], dpp2<0x4E>(pm[i]));                              \
        pm[i] = pmax2(pm[i], dpp2<0x141>(pm[i]));                             \
        pm[i] = pmax2(pm[i], dpp2<0x140>(pm[i]));                             \
        pm[i] = pmax2(pm[i], shx2(pm[i], 16));                                \
      }                                                                       \
      half2v ps[8];                                                           \
      _Pragma("unroll")                                                       \
      for (int i = 0; i < 8; ++i) {                                           \
        const float e0 = __expf(vp[2*i]     - (float)pm[i][0]);               \
        const float e1 = __expf(vp[2*i + 1] - (float)pm[i][1]);               \
        ps[i] = pkrtz(e0, e1);                                                \
      }                                                                       \
      _Pragma("unroll")                                                       \
      for (int i = 0; i < 8; ++i) {                                           \
        ps[i] = ps[i] + dpp2<0xB1>(ps[i]);                                    \
        ps[i] = ps[i] + dpp2<0x4E>(ps[i]);                                    \
        ps[i] = ps[i] + dpp2<0x141>(ps[i]);                                   \
        ps[i] = ps[i] + dpp2<0x140>(ps[i]);                                   \
        ps[i] = ps[i] + shx2(ps[i], 16);                                      \
      }                                                                       \
      if (c < 16) {                                                           \
        const half2v S = sel8(ps, c >> 1);                                    \
        const half2v M = sel8(pm, c >> 1);                                    \
        const float sum = (c & 1) ? (float)S[1] : (float)S[0];                \
        const float mx  = (c & 1) ? (float)M[1] : (float)M[0];                \
        const int rw = tile*32 + (c & 3) + 8*(c >> 2) + 4*h;                  \
        if (rw < N) out[rw] = mx + __logf(sum);                               \
      }                                                                       \
    }                                                                         \
  }

  for (int it = 0; it < iters; it += 2) {
    STEP(xA, xB, it);
    STEP(xB, xA, it + 1);
  }
#undef STEP
}

extern "C" void kernel_launch(void* const* d_in, const int* in_sizes, int n_in,
                              void* d_out, int out_size, void* d_ws, size_t ws_size,
                              hipStream_t stream) {
  (void)n_in; (void)out_size; (void)d_ws; (void)ws_size;
  const float* x  = (const float*)d_in[0];
  const float* MU = (const float*)d_in[1];
  const float* A  = (const float*)d_in[2];
  const float* D  = (const float*)d_in[3];
  const float* PI = (const float*)d_in[4];
  float* out = (float*)d_out;

  const int N = in_sizes[0] / DD;
  const int ntiles = (N + 31) / 32;
  const int iters  = (ntiles + NSLOT - 1) / NSLOT;
  hipLaunchKernelGGL(mfa_fused, dim3(NBLK), dim3(256), 0, stream,
                     x, MU, A, D, PI, out, N, ntiles, iters);
}